// Round 7
// baseline (211.537 us; speedup 1.0000x reference)
//
#include <hip/hip_runtime.h>

// YOLO loss reduction: B=512, 3136 cells/sample, 15 slots/cell, fp32, sum.
//
// R1 LDS 75us | R2 scatter 116us | R3 slot-stream 84us | R4 wave-DMA 95us |
// R5 fastmath-stream 76us | R6 forced-MLP 73.5us (VGPR=60: compiler sank
// loads past sched_barrier; MLP never happened).
// Diagnosis: all stream variants carry 2 per-float4 gate gathers (~60 cache
// lines each); vmcnt retires IN-ORDER, so every later stream load waits on
// the gather's line-serialization -> ~2.6 TB/s effective wall, no pipe busy.
//
// R7: quad-lane mapping. 4 cells == 15 float4s: 16-lane group owns a cell
// quad; lane r<15 loads float4 q*15+r (perfect coalescing, r=15 hole is
// inside already-fetched lines -> zero over-fetch). Slot/cell metadata per
// lane is LOOP-INVARIANT (hoisted). Gates come from 4 __shfl ops (DS pipe,
// register-to-register) instead of memory gathers -> VMEM queue carries
// only homogeneous dwordx4 streams, pipelined one step ahead.

#define EPSF 1e-9f
#define LN2F 0.69314718055994530942f

__global__ __launch_bounds__(256) void yolo_loss_quad(
    const float* __restrict__ o, const float* __restrict__ t,
    float* __restrict__ out_sum, unsigned n_quads, unsigned n_steps)
{
    const int tid  = threadIdx.x;
    const int lane = tid & 63;
    const unsigned r    = (unsigned)tid & 15u;   // float4 index within quad
    const bool     r_ok = r < 15u;
    const int      gsel = lane & 48;             // 16-lane group base lane

    // ---- loop-invariant per-lane metadata: elements e = 4r+j ----
    bool b_sq[4], b_z[4], b_b4[4], c_lo[4], c_hi[4];
    #pragma unroll
    for (int j = 0; j < 4; ++j) {
        const unsigned e = r * 4u + (unsigned)j;
        const unsigned c = e / 15u;              // 0..3 for r<15
        const unsigned s = e - c * 15u;
        b_sq[j] = (s == 2u) | (s == 3u);         // sqrt-diff slots (w,h)
        b_z [j] = (s == 1u) | (s == 14u);        // unused slots (y, class14)
        b_b4[j] = (s == 4u);                     // confidence (BCE)
        c_lo[j] = (c & 1u) != 0u;                // gate-select bits
        c_hi[j] = (c & 2u) != 0u;
    }

    const unsigned quads_per_step = (gridDim.x * 256u) >> 4;
    unsigned q = blockIdx.x * 16u + ((unsigned)tid >> 4);

    const float4* o4 = (const float4*)o;
    const float4* t4 = (const float4*)t;

    float acc = 0.f;

    // ---- software pipeline: prefetch one step ahead ----
    float4 co = make_float4(1.f, 1.f, 1.f, 1.f), ct = co;
    bool cur_ok = r_ok && (q < n_quads);
    if (cur_ok) { const unsigned fi = q * 15u + r; co = o4[fi]; ct = t4[fi]; }

    for (unsigned step = 1; step <= n_steps; ++step) {
        // prefetch next step (predicated; never taken-false for ref shape
        // except the nonexistent step n_steps)
        float4 no = make_float4(1.f, 1.f, 1.f, 1.f), nt = no;
        const unsigned qn = q + quads_per_step;
        const bool nxt_ok = (step < n_steps) && r_ok && (qn < n_quads);
        if (nxt_ok) { const unsigned fi = qn * 15u + r; no = o4[fi]; nt = t4[fi]; }

        // ---- compute current step ----
        // gate broadcast: cell-start elements live at static (lane, comp):
        // cell0 -> (r=0,.x)  cell1 -> e15=(r=3,.w)  cell2 -> e30=(r=7,.z)
        // cell3 -> e45=(r=11,.y)
        const float g0 = __shfl(co.x, gsel + 0,  64);
        const float g1 = __shfl(co.w, gsel + 3,  64);
        const float g2 = __shfl(co.z, gsel + 7,  64);
        const float g3 = __shfl(co.y, gsel + 11, 64);

        const float oe[4] = {co.x, co.y, co.z, co.w};
        const float te[4] = {ct.x, ct.y, ct.z, ct.w};

        // at most one slot-4 element per lane -> single BCE (2 v_log)
        float ob4 = oe[3], tb4 = te[3];
        #pragma unroll
        for (int j = 2; j >= 0; --j) {
            ob4 = b_b4[j] ? oe[j] : ob4;
            tb4 = b_b4[j] ? te[j] : tb4;
        }
        const float l1  = __log2f(ob4 + EPSF);
        const float l2  = __log2f((1.f - ob4) + EPSF);
        const float bce = -LN2F * (tb4 * l1 + (1.f - tb4) * l2);

        float s_iter = 0.f;
        #pragma unroll
        for (int j = 0; j < 4; ++j) {
            const float gate = c_hi[j] ? (c_lo[j] ? g3 : g2)
                                       : (c_lo[j] ? g1 : g0);
            const float ox = oe[j], tx = te[j];
            const float d  = ox - tx;
            float v = d * d;
            // (sqrt(a)-sqrt(b))^2 = a + b - 2*sqrt(ab): one v_sqrt_f32
            const float s23 = (ox + tx) - 2.f * __builtin_amdgcn_sqrtf(ox * tx);
            v = b_sq[j] ? s23 : v;
            v = b_b4[j] ? bce : v;
            v = b_z [j] ? 0.f : v;
            v = (gate != 0.f) ? v : 0.f;
            s_iter += v;
        }
        acc += cur_ok ? s_iter : 0.f;

        co = no; ct = nt; cur_ok = nxt_ok; q = qn;
    }

    // wave shuffle reduce -> cross-wave LDS -> one atomic per block
    #pragma unroll
    for (int off = 32; off; off >>= 1) acc += __shfl_down(acc, off, 64);
    __shared__ float wsum[4];
    if ((tid & 63) == 0) wsum[tid >> 6] = acc;
    __syncthreads();
    if (tid == 0) atomicAdd(out_sum, wsum[0] + wsum[1] + wsum[2] + wsum[3]);
}

// ---------- generic fallback (any n): R5-style guarded grid-stride ----------
__device__ __forceinline__ float bce_of(float ox, float tx) {
    const float l1 = __log2f(ox + EPSF);
    const float l2 = __log2f((1.f - ox) + EPSF);
    return -LN2F * (tx * l1 + (1.f - tx) * l2);
}

__global__ __launch_bounds__(256) void yolo_loss_generic(
    const float* __restrict__ o, const float* __restrict__ t,
    float* __restrict__ out_sum, int n_cells)
{
    const int tid = threadIdx.x;
    const int stride = gridDim.x * 256;
    float acc = 0.f;
    for (int c = blockIdx.x * 256 + tid; c < n_cells; c += stride) {
        const float* oc = o + (size_t)c * 15;
        const float* tc = t + (size_t)c * 15;
        const float o0 = oc[0];
        if (o0 != 0.f) {
            const float d0 = o0 - tc[0];
            const float w2 = oc[2] + tc[2] - 2.f * __builtin_amdgcn_sqrtf(oc[2] * tc[2]);
            const float h2 = oc[3] + tc[3] - 2.f * __builtin_amdgcn_sqrtf(oc[3] * tc[3]);
            float s = d0 * d0 + w2 + h2 + bce_of(oc[4], tc[4]);
            #pragma unroll
            for (int k = 5; k < 14; ++k) { const float d = tc[k] - oc[k]; s += d * d; }
            acc += s;
        }
    }
    #pragma unroll
    for (int off = 32; off; off >>= 1) acc += __shfl_down(acc, off, 64);
    __shared__ float wsum[4];
    if ((tid & 63) == 0) wsum[tid >> 6] = acc;
    __syncthreads();
    if (tid == 0) atomicAdd(out_sum, wsum[0] + wsum[1] + wsum[2] + wsum[3]);
}

extern "C" void kernel_launch(void* const* d_in, const int* in_sizes, int n_in,
                              void* d_out, int out_size, void* d_ws, size_t ws_size,
                              hipStream_t stream) {
    const float* o = (const float*)d_in[0];
    const float* t = (const float*)d_in[1];
    float* out = (float*)d_out;
    const int n = in_sizes[0];

    // d_out is poisoned 0xAA before every timed replay -> zero it on-stream.
    hipMemsetAsync(out, 0, sizeof(float), stream);

    if (n % 60 == 0) {
        const unsigned n_quads = (unsigned)(n / 60);     // 401,408 for ref
        // grid 1792 = 7 blocks/CU; quads/step = 28,672; ref: 14 exact steps
        unsigned grid = 1792;
        const unsigned qps = grid * 16u;
        const unsigned n_steps = (n_quads + qps - 1u) / qps;
        yolo_loss_quad<<<grid, 256, 0, stream>>>(o, t, out, n_quads, n_steps);
    } else {
        yolo_loss_generic<<<1792, 256, 0, stream>>>(o, t, out, n / 15);
    }
}